// Round 5
// baseline (298.549 us; speedup 1.0000x reference)
//
#include <hip/hip_runtime.h>
#include <math.h>

// ---------------- constants ----------------
#define NNPOS 2304            // 48*48
#define ROWS  18432           // 8 * 2304
#define NK    96              // K-steps: 48 mi-blocks x 2 halves of padded-64

// workspace layout (float offsets)
#define O_Q   0ul             // q_raw [row][64]
#define O_K   1179648ul       // k_raw [row][16]
#define O_V   1474560ul       // v_raw [row][32]
#define O_ST  2064384ul       // scale_q[64] bias_q[64] scale_v[32] bias_v[32] denomInv[128]
#define O_VP  2064704ul       // Vp_g bf16 [256][3072] padded (393216 float slots)
#define O_QP  2457920ul       // Qp fp32 [n][b][8][16]
#define O_LC  4817216ul       // lamc raw sums [b][16][32]
#define O_CR  4821312ul       // cor_reverse_ bf16 [row][128]
#define O_RT  6000960ul       // R_T bf16 [2 copies][16][9216] (2*73728 float slots)
#define O_WG  6148416ul       // Wg fp32 [o2][2] = Wmp@Wce
#define O_B2  6148672ul       // b2 fp32 [o2] = bmp - Wmp@bce
#define O_WB  6148800ul       // Wb bf16 [112][128]
#define O_PT  6155968ul       // part_q [64][128]
#define O_PV  6164160ul       // part_v [32][64]
#define O_PE  6166208ul       // part_e [8][8][16]
#define O_WFB 6167232ul       // Wf bf16 [128 o2][128 c]

typedef __bf16 bf16x8 __attribute__((ext_vector_type(8)));
typedef float  f32x4  __attribute__((ext_vector_type(4)));
typedef unsigned int u32;
struct __attribute__((packed, aligned(4))) bf16x8p { bf16x8 v; };

// ---------------- kernel: fold motion weights + convert qkv weights to bf16 ----------------
__global__ void k_fold(const float* __restrict__ Wcc, const float* __restrict__ Wce,
                       const float* __restrict__ Wmp, const float* __restrict__ bmp,
                       const float* __restrict__ bce, const float* __restrict__ Wq,
                       const float* __restrict__ Wk, const float* __restrict__ Wv,
                       float* __restrict__ ws) {
  const int t = threadIdx.x;
  const int g = blockIdx.x * 256 + t;
  const int o2 = g >> 7, c = g & 127;
  float acc = 0.f;
#pragma unroll 8
  for (int o = 0; o < 64; ++o) acc += Wmp[o2 * 64 + o] * Wcc[o * 128 + c];
  ((__bf16*)(ws + O_WFB))[o2 * 128 + c] = (__bf16)acc;
  if (blockIdx.x == 0 && t < 128) {
    float a0 = 0.f, a1 = 0.f, ab = 0.f;
#pragma unroll 8
    for (int o = 0; o < 64; ++o) {
      float w = Wmp[t * 64 + o];
      a0 += w * Wce[o * 2]; a1 += w * Wce[o * 2 + 1]; ab += w * bce[o];
    }
    ws[O_WG + t * 2] = a0; ws[O_WG + t * 2 + 1] = a1; ws[O_B2 + t] = bmp[t] - ab;
  }
  __bf16* wbp = (__bf16*)(ws + O_WB);
  if (g < 14336) {
    float w;
    if (g < 8192) w = Wq[g];
    else if (g < 10240) w = Wk[g - 8192];
    else w = Wv[g - 10240];
    wbp[g] = (__bf16)w;
  }
}

// ---------------- kernel 1: q,k,v via MFMA ----------------
__global__ __launch_bounds__(256) void k_qkv(const float* __restrict__ x,
                                             float* __restrict__ ws) {
  const int t = threadIdx.x;
  const int wave = t >> 6, lane = t & 63;
  const int lr = lane & 15, quad = lane >> 4;
  const int r0 = blockIdx.x * 64 + wave * 16;
  const int b = r0 / NNPOS;
  const int n0 = r0 - b * NNPOS;
  const size_t outbase = (size_t)(((b + 4) & 7)) * NNPOS + n0;

  const __bf16* wb = (const __bf16*)(ws + O_WB);
  const float* xrow = x + (size_t)(r0 + lr) * 128;

  f32x4 acc[7];
#pragma unroll
  for (int i = 0; i < 7; ++i) acc[i] = (f32x4){0.f, 0.f, 0.f, 0.f};

#pragma unroll
  for (int ks = 0; ks < 4; ++ks) {
    const float* ap = xrow + ks * 32 + quad * 8;
    float4 a0 = *(const float4*)(ap);
    float4 a1 = *(const float4*)(ap + 4);
    bf16x8 af;
    af[0] = (__bf16)a0.x; af[1] = (__bf16)a0.y; af[2] = (__bf16)a0.z; af[3] = (__bf16)a0.w;
    af[4] = (__bf16)a1.x; af[5] = (__bf16)a1.y; af[6] = (__bf16)a1.z; af[7] = (__bf16)a1.w;
#pragma unroll
    for (int ct = 0; ct < 7; ++ct) {
      bf16x8 bfrag = *(const bf16x8*)(wb + (ct * 16 + lr) * 128 + ks * 32 + quad * 8);
      acc[ct] = __builtin_amdgcn_mfma_f32_16x16x32_bf16(af, bfrag, acc[ct], 0, 0, 0);
    }
  }

#pragma unroll
  for (int ct = 0; ct < 7; ++ct) {
#pragma unroll
    for (int reg = 0; reg < 4; ++reg) {
      int m = quad * 4 + reg;
      int oc = ct * 16 + lr;
      float vvv = acc[ct][reg];
      if (ct < 4)      ws[O_Q + (size_t)(r0 + m) * 64 + oc] = vvv;
      else if (ct < 5) ws[O_K + (outbase + m) * 16 + (oc - 64)] = vvv;
      else             ws[O_V + (outbase + m) * 32 + (oc - 80)] = vvv;
    }
  }
}

// ---------------- kernel: R_T bf16 [16][9216], two copies (copy1 shifted by 1 elem) ----------------
__global__ void k_rt(const float* __restrict__ rel, float* __restrict__ ws) {
  __bf16* rt = (__bf16*)(ws + O_RT);
  int i = blockIdx.x * 256 + threadIdx.x;
  if (i < 144400) {                     // 95*95*16
    int kc = i & 15, rr = i >> 4;
    int ri = rr / 95, rj = rr - ri * 95;
    int d = ri * 96 + rj;
    __bf16 v = (__bf16)rel[i];
    rt[(size_t)kc * 9216 + d] = v;
    if (d > 0) rt[147456ul + (size_t)kc * 9216 + d - 1] = v;   // rt1[i] = rt0[i+1]
  }
}

// ---------------- kernel: zero Vp pad + lamc accumulator ----------------
__global__ void k_zero(float* __restrict__ ws) {
  __bf16* vp = (__bf16*)(ws + O_VP);
  int i = blockIdx.x * 256 + threadIdx.x;   // < 24576
  if (i < 4096) ws[O_LC + i] = 0.f;
  int bv = i / 96, rem = i - bv * 96;
  int mi = rem >> 1, h8 = rem & 1;
  uint4 z; z.x = 0; z.y = 0; z.z = 0; z.w = 0;
  *(uint4*)(vp + (size_t)bv * 3072 + mi * 64 + 48 + h8 * 8) = z;
}

// ---------------- kernel 2a: stats partials (coalesced) ----------------
__global__ void k_stats1(float* __restrict__ ws) {
  const int t = threadIdx.x, blk = blockIdx.x;
  __shared__ float sh[512];
  if (blk < 64) {
    const int ch = t & 63, rsub = t >> 6;
    const float* src = ws + O_Q;
    const int r0 = blk * 288;
    float s = 0.f, s2 = 0.f;
#pragma unroll 4
    for (int i = 0; i < 72; ++i) {
      float v = src[(size_t)(r0 + rsub + i * 4) * 64 + ch];
      s += v; s2 += v * v;
    }
    sh[t] = s; sh[256 + t] = s2;
    __syncthreads();
    if (t < 64) {
      float S = sh[t] + sh[t + 64] + sh[t + 128] + sh[t + 192];
      float S2 = sh[256 + t] + sh[256 + t + 64] + sh[256 + t + 128] + sh[256 + t + 192];
      ws[O_PT + blk * 128 + t * 2] = S; ws[O_PT + blk * 128 + t * 2 + 1] = S2;
    }
  } else if (blk < 96) {
    const int j = blk - 64;
    const int ch = t & 31, rsub = t >> 5;
    const float* src = ws + O_V;
    const int r0 = j * 576;
    float s = 0.f, s2 = 0.f;
#pragma unroll 4
    for (int i = 0; i < 72; ++i) {
      float v = src[(size_t)(r0 + rsub + i * 8) * 32 + ch];
      s += v; s2 += v * v;
    }
    sh[t] = s; sh[256 + t] = s2;
    __syncthreads();
    if (t < 32) {
      float S = 0.f, S2 = 0.f;
#pragma unroll
      for (int k = 0; k < 8; ++k) { S += sh[t + k * 32]; S2 += sh[256 + t + k * 32]; }
      ws[O_PV + j * 64 + t * 2] = S; ws[O_PV + j * 64 + t * 2 + 1] = S2;
    }
  } else {
    const int idx = blk - 96;
    const int b = idx >> 3, sl = idx & 7;
    const int kc = t & 15, rsub = t >> 4;
    const int r0 = b * 2304 + sl * 288;
    float s = 0.f;
#pragma unroll 2
    for (int i = 0; i < 18; ++i)
      s += __expf(ws[O_K + (size_t)(r0 + rsub + i * 16) * 16 + kc]);
    sh[t] = s;
    __syncthreads();
    if (t < 16) {
      float S = 0.f;
#pragma unroll
      for (int k = 0; k < 16; ++k) S += sh[t + k * 16];
      ws[O_PE + b * 128 + sl * 16 + t] = S;
    }
  }
}

// ---------------- kernel 2b: finalize stats ----------------
__global__ void k_stats2(const float* __restrict__ gq, const float* __restrict__ bq,
                         const float* __restrict__ gv, const float* __restrict__ bv,
                         float* __restrict__ ws) {
  const int t = threadIdx.x;
  if (t < 64) {
    float S = 0.f, S2 = 0.f;
    for (int i = 0; i < 64; ++i) { S += ws[O_PT + i * 128 + t * 2]; S2 += ws[O_PT + i * 128 + t * 2 + 1]; }
    float mu = S / 18432.f, var = S2 / 18432.f - mu * mu;
    float sc = gq[t] * rsqrtf(var + 1e-5f);
    ws[O_ST + t] = sc; ws[O_ST + 64 + t] = bq[t] - mu * sc;
  } else if (t < 96) {
    int ch = t - 64;
    float S = 0.f, S2 = 0.f;
    for (int i = 0; i < 32; ++i) { S += ws[O_PV + i * 64 + ch * 2]; S2 += ws[O_PV + i * 64 + ch * 2 + 1]; }
    float mu = S / 18432.f, var = S2 / 18432.f - mu * mu;
    float sc = gv[ch] * rsqrtf(var + 1e-5f);
    ws[O_ST + 128 + ch] = sc; ws[O_ST + 160 + ch] = bv[ch] - mu * sc;
  } else if (t < 224) {
    int idx = t - 96; int b = idx >> 4, kc = idx & 15;
    float S = 0.f;
#pragma unroll
    for (int sl = 0; sl < 8; ++sl) S += ws[O_PE + b * 128 + sl * 16 + kc];
    ws[O_ST + 192 + idx] = 1.f / S;
  }
}

// ---------------- kernel: build Vp_g via LDS transpose (contiguous packed writes) ----------------
__global__ void k_vp(float* __restrict__ ws) {
  const int b = blockIdx.x / 48, mi = blockIdx.x - b * 48;
  const int t = threadIdx.x;
  __shared__ float Vn[48 * 33];
  const float* st = ws + O_ST;
  const int r0 = b * 2304 + mi * 48;
#pragma unroll
  for (int i = t; i < 1536; i += 256) {
    int r = i >> 5, j = i & 31;
    Vn[r * 33 + j] = ws[O_V + (size_t)(r0 + r) * 32 + j] * st[128 + j] + st[160 + j];
  }
  __syncthreads();
  __bf16* vp = (__bf16*)(ws + O_VP);
  const int j = t >> 3, seg = t & 7;
  unsigned short u[6];
#pragma unroll
  for (int q = 0; q < 6; ++q)
    u[q] = __builtin_bit_cast(unsigned short, (__bf16)Vn[(seg * 6 + q) * 33 + j]);
  u32 w0 = (u32)u[0] | ((u32)u[1] << 16);
  u32 w1 = (u32)u[2] | ((u32)u[3] << 16);
  u32 w2 = (u32)u[4] | ((u32)u[5] << 16);
  u32* dst = (u32*)(vp + (size_t)(b * 32 + j) * 3072 + mi * 64 + seg * 6);
  dst[0] = w0; dst[1] = w1; dst[2] = w2;
}

// ---------------- kernel 3: Qp (Q' + cor_embed 8 virtual heads) ----------------
__global__ void k_prep(const float* __restrict__ cor, const float* __restrict__ Wce,
                       const float* __restrict__ bce, float* __restrict__ ws) {
  const int t = threadIdx.x;
  const int rl = t >> 5, j = t & 31;
  const int rid = blockIdx.x * 8 + rl;
  const int b = rid / NNPOS, n = rid - b * NNPOS;
  const float* st = ws + O_ST;
  float c0 = cor[rid * 2], c1 = cor[rid * 2 + 1];
#pragma unroll
  for (int ch = j; ch < 64; ch += 32) {
    float qn = ws[O_Q + (size_t)rid * 64 + ch] * st[ch] + st[64 + ch];
    ws[O_QP + (size_t)(n * 8 + b) * 128 + ch] = qn;
    float ce = c0 * Wce[ch * 2] + c1 * Wce[ch * 2 + 1] + bce[ch];
    ws[O_QP + (size_t)(n * 8 + b) * 128 + 64 + ch] = ce;
  }
}

// ---------------- kernel 4: lamc raw sums (288 blocks, LDS-staged, atomic) ----------------
__global__ void k_lamc(float* __restrict__ ws) {
  const int b = blockIdx.x / 36, sl = blockIdx.x - b * 36;
  const int t = threadIdx.x;
  __shared__ float eK[16][16];
  __shared__ float Vn[16][33];
  const float* st = ws + O_ST;
  const int kc = t & 15, vp_ = t >> 4;
  const int v0 = vp_ * 2, v1 = v0 + 1;
  float a0 = 0.f, a1 = 0.f;
  const int m0 = b * 2304 + sl * 64;
  const int jj = t & 31, rw = t >> 5;
  const float scj = st[128 + jj], bij = st[160 + jj];
  for (int ch = 0; ch < 4; ++ch) {
    const int mbase = m0 + ch * 16;
    eK[t >> 4][t & 15] = __expf(ws[O_K + (size_t)(mbase + (t >> 4)) * 16 + (t & 15)]);
    Vn[rw][jj]     = ws[O_V + (size_t)(mbase + rw) * 32 + jj] * scj + bij;
    Vn[rw + 8][jj] = ws[O_V + (size_t)(mbase + rw + 8) * 32 + jj] * scj + bij;
    __syncthreads();
#pragma unroll
    for (int m = 0; m < 16; ++m) {
      float e = eK[m][kc];
      a0 += e * Vn[m][v0];
      a1 += e * Vn[m][v1];
    }
    __syncthreads();
  }
  atomicAdd(&ws[O_LC + (size_t)(b * 16 + kc) * 32 + v0], a0);
  atomicAdd(&ws[O_LC + (size_t)(b * 16 + kc) * 32 + v1], a1);
}

// ---------------- kernel 5: lamp GEMM v3 ----------------
// 2-wave blocks, 128 rows (8n x 16kc) x 64 cols; grid (288, 4).
// A read directly from dual-parity R_T (global, L2); B double-buffered in LDS,
// one barrier per K-step; fused Y epilogue.
__global__ __launch_bounds__(128, 3) void k_lamp(float* __restrict__ ws,
                                                 float* __restrict__ out) {
  __shared__ __align__(16) char smem[17408];
  bf16x8* Bs16 = (bf16x8*)smem;        // 2 x 256 units (8 KB)
  float* Cs = (float*)smem;            // epilogue [64][68]

  const int t = threadIdx.x;
  const int bx = blockIdx.x;
  const int ni = bx / 6;
  const int sset = bx - ni * 6;
  const int s0 = (sset < 3) ? sset * 16 : (sset - 3) * 16 + 1;
  const int by = blockIdx.y;
  const int colbase = by * 64;
  const int w = t >> 6, lane = t & 63;
  const int lr = lane & 15, quad = lane >> 4;

  const __bf16* vp = (const __bf16*)(ws + O_VP);
  const __bf16* rtb = (const __bf16*)(ws + O_RT);

  // B staging: 256 16B units per buffer, swizzled
  const int u0 = t, u1 = t + 128;
  const int c0 = u0 >> 2, p0 = ((u0 & 3) - (c0 >> 1)) & 3;
  const int c1 = u1 >> 2, p1 = ((u1 & 3) - (c1 >> 1)) & 3;
  const __bf16* gB0 = vp + (size_t)(colbase + c0) * 3072 + p0 * 8;
  const __bf16* gB1 = vp + (size_t)(colbase + c1) * 3072 + p1 * 8;

  // A direct-global base (parity-corrected)
  const int parity = (s0 + 1) & 1;
  const __bf16* baseA = rtb + (size_t)parity * 147456 +
                        (size_t)lr * 9216 + quad * 8 - 2 * (w * 4);

  f32x4 acc[4][4];
  {
    f32x4 zz = {0.f, 0.f, 0.f, 0.f};
#pragma unroll
    for (int i = 0; i < 4; ++i)
#pragma unroll
      for (int j = 0; j < 4; ++j) acc[i][j] = zz;
  }

  bf16x8 afA[4], afB[4], vb0, vb1;

  auto loadA = [&](int ksn, bf16x8* dst) {
    int mi = ksn >> 1, mj0 = (ksn & 1) << 5;
    const __bf16* p = baseA + (96 * (mi - ni + 47) + mj0 - s0 + 47 - parity);
#pragma unroll
    for (int rt = 0; rt < 4; ++rt)
      dst[rt] = ((const bf16x8p*)(p - 2 * rt))->v;
  };
  auto loadB = [&](int ksn) {
    int k0 = ksn * 32;
    vb0 = *(const bf16x8*)(gB0 + k0);
    vb1 = *(const bf16x8*)(gB1 + k0);
  };

  // prologue: buf0 = B0, regs = B1, afA = A0
  loadB(0);
  Bs16[u0] = vb0; Bs16[u1] = vb1;
  loadA(0, afA);
  loadB(1);
  __syncthreads();

  for (int ks = 0; ks < NK; ks += 2) {
    // even step: frags from buf0; store B(ks+1)->buf1
    Bs16[256 + u0] = vb0; Bs16[256 + u1] = vb1;
    loadB(ks + 2 < NK ? ks + 2 : NK - 1);
    loadA(ks + 1, afB);
#pragma unroll
    for (int ct = 0; ct < 4; ++ct) {
      int col = ct * 16 + lr;
      bf16x8 bfr = Bs16[col * 4 + ((quad + (col >> 1)) & 3)];
#pragma unroll
      for (int rt = 0; rt < 4; ++rt)
        acc[rt][ct] = __builtin_amdgcn_mfma_f32_16x16x32_bf16(afA[rt], bfr, acc[rt][ct], 0, 0, 0);
    }
    __syncthreads();
    // odd step: frags from buf1; store B(ks+2)->buf0
    Bs16[u0] = vb0; Bs16[u1] = vb1;
    loadB(ks + 3 < NK ? ks + 3 : NK - 1);
    if (ks + 2 < NK) loadA(ks + 2, afA);
#pragma unroll
    for (int ct = 0; ct < 4; ++ct) {
      int col = ct * 16 + lr;
      bf16x8 bfr = Bs16[256 + col * 4 + ((quad + (col >> 1)) & 3)];
#pragma unroll
      for (int rt = 0; rt < 4; ++rt)
        acc[rt][ct] = __builtin_amdgcn_mfma_f32_16x16x32_bf16(afB[rt], bfr, acc[rt][ct], 0, 0, 0);
    }
    __syncthreads();
  }

  // epilogue: Y = sum_kc Qp * (lamp + lamc*dinv)
  const float* lamcp = ws + O_LC;
  const float* Qp = ws + O_QP;
  __bf16* CRb = (__bf16*)(ws + O_CR);
  const int s = t >> 5, vv = t & 31;

  for (int h = 0; h < 2; ++h) {
    __syncthreads();
    if (w == h) {
#pragma unroll
      for (int rt = 0; rt < 4; ++rt) {
#pragma unroll
        for (int ct = 0; ct < 4; ++ct) {
          int col = ct * 16 + lr;
          int bb = by * 2 + (col >> 5);
          int vl = col & 31;
#pragma unroll
          for (int reg = 0; reg < 4; ++reg) {
            int row = rt * 16 + quad * 4 + reg;
            int kc = row & 15;
            float dinv = ws[O_ST + 192 + bb * 16 + kc];
            Cs[row * 68 + col] = acc[rt][ct][reg] + lamcp[(bb * 16 + kc) * 32 + vl] * dinv;
          }
        }
      }
    }
    __syncthreads();
#pragma unroll
    for (int i = 0; i < 16; ++i) {
      int combo = s * 16 + i;
      int hp = combo & 7, bl = (combo >> 3) & 1, nr = combo >> 4;
      int n = ni * 48 + s0 + 2 * (h * 4 + nr);
      int bb = by * 2 + bl;
      const float* qrow = Qp + ((size_t)(n * 8 + bb) * 8 + hp) * 16;
      const float* crow = Cs + (nr * 16) * 68 + bl * 32 + vv;
      float y = 0.f;
#pragma unroll
      for (int kc = 0; kc < 16; ++kc) y += qrow[kc] * crow[kc * 68];
      size_t idx = (size_t)(bb * NNPOS + n) * 128 + (hp & 3) * 32 + vv;
      if (hp < 4) out[idx] = y;
      else        CRb[idx] = (__bf16)y;
    }
  }
}

// ---------------- kernel: motion via MFMA ----------------
__global__ __launch_bounds__(256) void k_motion(const float* __restrict__ cor,
                                                float* __restrict__ ws,
                                                float* __restrict__ out) {
  const int t = threadIdx.x;
  const int wave = t >> 6, lane = t & 63;
  const int lr = lane & 15, quad = lane >> 4;
  const int r0 = blockIdx.x * 64 + wave * 16;
  const __bf16* crb = (const __bf16*)(ws + O_CR);
  const __bf16* wfb = (const __bf16*)(ws + O_WFB);

  f32x4 acc[8];
#pragma unroll
  for (int i = 0; i < 8; ++i) acc[i] = (f32x4){0.f, 0.f, 0.f, 0.f};

#pragma unroll
  for (int ks = 0; ks < 4; ++ks) {
    bf16x8 af = *(const bf16x8*)(crb + (size_t)(r0 + lr) * 128 + ks * 32 + quad * 8);
#pragma unroll
    for (int ct = 0; ct < 8; ++ct) {
      bf16x8 bfrag = *(const bf16x8*)(wfb + (ct * 16 + lr) * 128 + ks * 32 + quad * 8);
      acc[ct] = __builtin_amdgcn_mfma_f32_16x16x32_bf16(af, bfrag, acc[ct], 0, 0, 0);
    }
  }

#pragma unroll
  for (int reg = 0; reg < 4; ++reg) {
    int row = r0 + quad * 4 + reg;
    float c0 = cor[row * 2], c1 = cor[row * 2 + 1];
#pragma unroll
    for (int ct = 0; ct < 8; ++ct) {
      int o2 = ct * 16 + lr;
      float y = acc[ct][reg] + ws[O_B2 + o2] - c0 * ws[O_WG + o2 * 2] - c1 * ws[O_WG + o2 * 2 + 1];
      out[2359296ul + (size_t)row * 128 + o2] = y;
    }
  }
}

// ---------------- launcher ----------------
extern "C" void kernel_launch(void* const* d_in, const int* in_sizes, int n_in,
                              void* d_out, int out_size, void* d_ws, size_t ws_size,
                              hipStream_t stream) {
  const float* x   = (const float*)d_in[0];
  const float* cor = (const float*)d_in[1];
  const float* Wq  = (const float*)d_in[2];
  const float* Wk  = (const float*)d_in[3];
  const float* Wv  = (const float*)d_in[4];
  const float* Wce = (const float*)d_in[5];
  const float* bce = (const float*)d_in[6];
  const float* Wcc = (const float*)d_in[7];
  const float* Wmp = (const float*)d_in[8];
  const float* bmp = (const float*)d_in[9];
  const float* gq  = (const float*)d_in[10];
  const float* bq  = (const float*)d_in[11];
  const float* gv  = (const float*)d_in[12];
  const float* bv  = (const float*)d_in[13];
  const float* rel = (const float*)d_in[14];
  float* out = (float*)d_out;
  float* ws  = (float*)d_ws;

  k_fold  <<<64, 256, 0, stream>>>(Wcc, Wce, Wmp, bmp, bce, Wq, Wk, Wv, ws);
  k_qkv   <<<288, 256, 0, stream>>>(x, ws);
  k_rt    <<<565, 256, 0, stream>>>(rel, ws);
  k_zero  <<<96, 256, 0, stream>>>(ws);
  k_stats1<<<160, 256, 0, stream>>>(ws);
  k_stats2<<<1, 256, 0, stream>>>(gq, bq, gv, bv, ws);
  k_vp    <<<384, 256, 0, stream>>>(ws);
  k_lamc  <<<288, 256, 0, stream>>>(ws);
  k_prep  <<<2304, 256, 0, stream>>>(cor, Wce, bce, ws);
  k_lamp  <<<dim3(288, 4), 128, 0, stream>>>(ws, out);
  k_motion<<<288, 256, 0, stream>>>(cor, ws, out);
}

// Round 6
// 267.988 us; speedup vs baseline: 1.1140x; 1.1140x over previous
//
#include <hip/hip_runtime.h>
#include <math.h>
#include <stdint.h>

// ---------------- constants ----------------
#define NNPOS 2304            // 48*48
#define ROWS  18432           // 8 * 2304
#define NK    96              // K-steps: 48 mi-blocks x 2 halves of padded-64

// workspace layout (float offsets)
#define O_Q   0ul             // q_raw [row][64]
#define O_K   1179648ul       // k_raw [row][16]
#define O_V   1474560ul       // v_raw [row][32]
#define O_ST  2064384ul       // scale_q[64] bias_q[64] scale_v[32] bias_v[32] denomInv[128]
#define O_VP  2064704ul       // Vp_g bf16 [256][3072] padded
#define O_QP  2457920ul       // Qp fp32 [n][b][8][16]
#define O_LC  4817216ul       // lamc raw sums [b][16][32]
#define O_CR  4821312ul       // cor_reverse_ bf16 [row][128]
#define O_RT  6000960ul       // R_T bf16 [16][9216]
#define O_WG  6148416ul       // Wg fp32 [o2][2] = Wmp@Wce
#define O_B2  6148672ul       // b2 fp32 [o2] = bmp - Wmp@bce
#define O_WB  6148800ul       // Wb bf16 [112][128]
#define O_PT  6155968ul       // part_q [64][128]
#define O_PV  6164160ul       // part_v [32][64]
#define O_PE  6166208ul       // part_e [8][8][16]
#define O_WFB 6167232ul       // Wf bf16 [128 o2][128 c]

typedef __bf16 bf16x8 __attribute__((ext_vector_type(8)));
typedef float  f32x4  __attribute__((ext_vector_type(4)));
typedef unsigned int u32;
typedef u32 u32x4 __attribute__((ext_vector_type(4)));

__device__ __forceinline__ void gll16(const void* g, void* l) {
  auto gp = (const __attribute__((address_space(1))) unsigned char*)(uintptr_t)g;
  auto lp = (__attribute__((address_space(3))) unsigned char*)(u32)(uintptr_t)l;
  __builtin_amdgcn_global_load_lds(gp, lp, 16, 0, 0);
}

// ---------------- kernel: fold motion weights + convert qkv weights to bf16 ----------------
__global__ void k_fold(const float* __restrict__ Wcc, const float* __restrict__ Wce,
                       const float* __restrict__ Wmp, const float* __restrict__ bmp,
                       const float* __restrict__ bce, const float* __restrict__ Wq,
                       const float* __restrict__ Wk, const float* __restrict__ Wv,
                       float* __restrict__ ws) {
  const int t = threadIdx.x;
  const int g = blockIdx.x * 256 + t;
  const int o2 = g >> 7, c = g & 127;
  float acc = 0.f;
#pragma unroll 8
  for (int o = 0; o < 64; ++o) acc += Wmp[o2 * 64 + o] * Wcc[o * 128 + c];
  ((__bf16*)(ws + O_WFB))[o2 * 128 + c] = (__bf16)acc;
  if (blockIdx.x == 0 && t < 128) {
    float a0 = 0.f, a1 = 0.f, ab = 0.f;
#pragma unroll 8
    for (int o = 0; o < 64; ++o) {
      float w = Wmp[t * 64 + o];
      a0 += w * Wce[o * 2]; a1 += w * Wce[o * 2 + 1]; ab += w * bce[o];
    }
    ws[O_WG + t * 2] = a0; ws[O_WG + t * 2 + 1] = a1; ws[O_B2 + t] = bmp[t] - ab;
  }
  __bf16* wbp = (__bf16*)(ws + O_WB);
  if (g < 14336) {
    float w;
    if (g < 8192) w = Wq[g];
    else if (g < 10240) w = Wk[g - 8192];
    else w = Wv[g - 10240];
    wbp[g] = (__bf16)w;
  }
}

// ---------------- kernel 1: q,k,v via MFMA ----------------
__global__ __launch_bounds__(256) void k_qkv(const float* __restrict__ x,
                                             float* __restrict__ ws) {
  const int t = threadIdx.x;
  const int wave = t >> 6, lane = t & 63;
  const int lr = lane & 15, quad = lane >> 4;
  const int r0 = blockIdx.x * 64 + wave * 16;
  const int b = r0 / NNPOS;
  const int n0 = r0 - b * NNPOS;
  const size_t outbase = (size_t)(((b + 4) & 7)) * NNPOS + n0;

  const __bf16* wb = (const __bf16*)(ws + O_WB);
  const float* xrow = x + (size_t)(r0 + lr) * 128;

  f32x4 acc[7];
#pragma unroll
  for (int i = 0; i < 7; ++i) acc[i] = (f32x4){0.f, 0.f, 0.f, 0.f};

#pragma unroll
  for (int ks = 0; ks < 4; ++ks) {
    const float* ap = xrow + ks * 32 + quad * 8;
    float4 a0 = *(const float4*)(ap);
    float4 a1 = *(const float4*)(ap + 4);
    bf16x8 af;
    af[0] = (__bf16)a0.x; af[1] = (__bf16)a0.y; af[2] = (__bf16)a0.z; af[3] = (__bf16)a0.w;
    af[4] = (__bf16)a1.x; af[5] = (__bf16)a1.y; af[6] = (__bf16)a1.z; af[7] = (__bf16)a1.w;
#pragma unroll
    for (int ct = 0; ct < 7; ++ct) {
      bf16x8 bfrag = *(const bf16x8*)(wb + (ct * 16 + lr) * 128 + ks * 32 + quad * 8);
      acc[ct] = __builtin_amdgcn_mfma_f32_16x16x32_bf16(af, bfrag, acc[ct], 0, 0, 0);
    }
  }

#pragma unroll
  for (int ct = 0; ct < 7; ++ct) {
#pragma unroll
    for (int reg = 0; reg < 4; ++reg) {
      int m = quad * 4 + reg;
      int oc = ct * 16 + lr;
      float vvv = acc[ct][reg];
      if (ct < 4)      ws[O_Q + (size_t)(r0 + m) * 64 + oc] = vvv;
      else if (ct < 5) ws[O_K + (outbase + m) * 16 + (oc - 64)] = vvv;
      else             ws[O_V + (outbase + m) * 32 + (oc - 80)] = vvv;
    }
  }
}

// ---------------- kernel: transpose rel_pos_emb -> R_T bf16 [16][96*96] ----------------
__global__ void k_rt(const float* __restrict__ rel, float* __restrict__ ws) {
  __bf16* rt = (__bf16*)(ws + O_RT);
  int i = blockIdx.x * 256 + threadIdx.x;
  if (i < 144400) {
    int kc = i & 15, rr = i >> 4;
    int ri = rr / 95, rj = rr - ri * 95;
    rt[(size_t)kc * 9216 + ri * 96 + rj] = (__bf16)rel[i];
  }
}

// ---------------- kernel: zero Vp pad + lamc accumulator ----------------
__global__ void k_zero(float* __restrict__ ws) {
  __bf16* vp = (__bf16*)(ws + O_VP);
  int i = blockIdx.x * 256 + threadIdx.x;   // < 24576
  if (i < 4096) ws[O_LC + i] = 0.f;
  int bv = i / 96, rem = i - bv * 96;
  int mi = rem >> 1, h8 = rem & 1;
  uint4 z; z.x = 0; z.y = 0; z.z = 0; z.w = 0;
  *(uint4*)(vp + (size_t)bv * 3072 + mi * 64 + 48 + h8 * 8) = z;
}

// ---------------- kernel 2a: stats partials (coalesced) ----------------
__global__ void k_stats1(float* __restrict__ ws) {
  const int t = threadIdx.x, blk = blockIdx.x;
  __shared__ float sh[512];
  if (blk < 64) {
    const int ch = t & 63, rsub = t >> 6;
    const float* src = ws + O_Q;
    const int r0 = blk * 288;
    float s = 0.f, s2 = 0.f;
#pragma unroll 4
    for (int i = 0; i < 72; ++i) {
      float v = src[(size_t)(r0 + rsub + i * 4) * 64 + ch];
      s += v; s2 += v * v;
    }
    sh[t] = s; sh[256 + t] = s2;
    __syncthreads();
    if (t < 64) {
      float S = sh[t] + sh[t + 64] + sh[t + 128] + sh[t + 192];
      float S2 = sh[256 + t] + sh[256 + t + 64] + sh[256 + t + 128] + sh[256 + t + 192];
      ws[O_PT + blk * 128 + t * 2] = S; ws[O_PT + blk * 128 + t * 2 + 1] = S2;
    }
  } else if (blk < 96) {
    const int j = blk - 64;
    const int ch = t & 31, rsub = t >> 5;
    const float* src = ws + O_V;
    const int r0 = j * 576;
    float s = 0.f, s2 = 0.f;
#pragma unroll 4
    for (int i = 0; i < 72; ++i) {
      float v = src[(size_t)(r0 + rsub + i * 8) * 32 + ch];
      s += v; s2 += v * v;
    }
    sh[t] = s; sh[256 + t] = s2;
    __syncthreads();
    if (t < 32) {
      float S = 0.f, S2 = 0.f;
#pragma unroll
      for (int k = 0; k < 8; ++k) { S += sh[t + k * 32]; S2 += sh[256 + t + k * 32]; }
      ws[O_PV + j * 64 + t * 2] = S; ws[O_PV + j * 64 + t * 2 + 1] = S2;
    }
  } else {
    const int idx = blk - 96;
    const int b = idx >> 3, sl = idx & 7;
    const int kc = t & 15, rsub = t >> 4;
    const int r0 = b * 2304 + sl * 288;
    float s = 0.f;
#pragma unroll 2
    for (int i = 0; i < 18; ++i)
      s += __expf(ws[O_K + (size_t)(r0 + rsub + i * 16) * 16 + kc]);
    sh[t] = s;
    __syncthreads();
    if (t < 16) {
      float S = 0.f;
#pragma unroll
      for (int k = 0; k < 16; ++k) S += sh[t + k * 16];
      ws[O_PE + b * 128 + sl * 16 + t] = S;
    }
  }
}

// ---------------- kernel 2b: finalize stats ----------------
__global__ void k_stats2(const float* __restrict__ gq, const float* __restrict__ bq,
                         const float* __restrict__ gv, const float* __restrict__ bv,
                         float* __restrict__ ws) {
  const int t = threadIdx.x;
  if (t < 64) {
    float S = 0.f, S2 = 0.f;
    for (int i = 0; i < 64; ++i) { S += ws[O_PT + i * 128 + t * 2]; S2 += ws[O_PT + i * 128 + t * 2 + 1]; }
    float mu = S / 18432.f, var = S2 / 18432.f - mu * mu;
    float sc = gq[t] * rsqrtf(var + 1e-5f);
    ws[O_ST + t] = sc; ws[O_ST + 64 + t] = bq[t] - mu * sc;
  } else if (t < 96) {
    int ch = t - 64;
    float S = 0.f, S2 = 0.f;
    for (int i = 0; i < 32; ++i) { S += ws[O_PV + i * 64 + ch * 2]; S2 += ws[O_PV + i * 64 + ch * 2 + 1]; }
    float mu = S / 18432.f, var = S2 / 18432.f - mu * mu;
    float sc = gv[ch] * rsqrtf(var + 1e-5f);
    ws[O_ST + 128 + ch] = sc; ws[O_ST + 160 + ch] = bv[ch] - mu * sc;
  } else if (t < 224) {
    int idx = t - 96; int b = idx >> 4, kc = idx & 15;
    float S = 0.f;
#pragma unroll
    for (int sl = 0; sl < 8; ++sl) S += ws[O_PE + b * 128 + sl * 16 + kc];
    ws[O_ST + 192 + idx] = 1.f / S;
  }
}

// ---------------- kernel: build Vp_g via LDS transpose ----------------
__global__ void k_vp(float* __restrict__ ws) {
  const int b = blockIdx.x / 48, mi = blockIdx.x - b * 48;
  const int t = threadIdx.x;
  __shared__ float Vn[48 * 33];
  const float* st = ws + O_ST;
  const int r0 = b * 2304 + mi * 48;
#pragma unroll
  for (int i = t; i < 1536; i += 256) {
    int r = i >> 5, j = i & 31;
    Vn[r * 33 + j] = ws[O_V + (size_t)(r0 + r) * 32 + j] * st[128 + j] + st[160 + j];
  }
  __syncthreads();
  __bf16* vp = (__bf16*)(ws + O_VP);
  const int j = t >> 3, seg = t & 7;
  unsigned short u[6];
#pragma unroll
  for (int q = 0; q < 6; ++q)
    u[q] = __builtin_bit_cast(unsigned short, (__bf16)Vn[(seg * 6 + q) * 33 + j]);
  u32 w0 = (u32)u[0] | ((u32)u[1] << 16);
  u32 w1 = (u32)u[2] | ((u32)u[3] << 16);
  u32 w2 = (u32)u[4] | ((u32)u[5] << 16);
  u32* dst = (u32*)(vp + (size_t)(b * 32 + j) * 3072 + mi * 64 + seg * 6);
  dst[0] = w0; dst[1] = w1; dst[2] = w2;
}

// ---------------- kernel 3: Qp (Q' + cor_embed 8 virtual heads) ----------------
__global__ void k_prep(const float* __restrict__ cor, const float* __restrict__ Wce,
                       const float* __restrict__ bce, float* __restrict__ ws) {
  const int t = threadIdx.x;
  const int rl = t >> 5, j = t & 31;
  const int rid = blockIdx.x * 8 + rl;
  const int b = rid / NNPOS, n = rid - b * NNPOS;
  const float* st = ws + O_ST;
  float c0 = cor[rid * 2], c1 = cor[rid * 2 + 1];
#pragma unroll
  for (int ch = j; ch < 64; ch += 32) {
    float qn = ws[O_Q + (size_t)rid * 64 + ch] * st[ch] + st[64 + ch];
    ws[O_QP + (size_t)(n * 8 + b) * 128 + ch] = qn;
    float ce = c0 * Wce[ch * 2] + c1 * Wce[ch * 2 + 1] + bce[ch];
    ws[O_QP + (size_t)(n * 8 + b) * 128 + 64 + ch] = ce;
  }
}

// ---------------- kernel 4: lamc raw sums (288 blocks, LDS-staged, atomic) ----------------
__global__ void k_lamc(float* __restrict__ ws) {
  const int b = blockIdx.x / 36, sl = blockIdx.x - b * 36;
  const int t = threadIdx.x;
  __shared__ float eK[16][16];
  __shared__ float Vn[16][33];
  const float* st = ws + O_ST;
  const int kc = t & 15, vp_ = t >> 4;
  const int v0 = vp_ * 2, v1 = v0 + 1;
  float a0 = 0.f, a1 = 0.f;
  const int m0 = b * 2304 + sl * 64;
  const int jj = t & 31, rw = t >> 5;
  const float scj = st[128 + jj], bij = st[160 + jj];
  for (int ch = 0; ch < 4; ++ch) {
    const int mbase = m0 + ch * 16;
    eK[t >> 4][t & 15] = __expf(ws[O_K + (size_t)(mbase + (t >> 4)) * 16 + (t & 15)]);
    Vn[rw][jj]     = ws[O_V + (size_t)(mbase + rw) * 32 + jj] * scj + bij;
    Vn[rw + 8][jj] = ws[O_V + (size_t)(mbase + rw + 8) * 32 + jj] * scj + bij;
    __syncthreads();
#pragma unroll
    for (int m = 0; m < 16; ++m) {
      float e = eK[m][kc];
      a0 += e * Vn[m][v0];
      a1 += e * Vn[m][v1];
    }
    __syncthreads();
  }
  atomicAdd(&ws[O_LC + (size_t)(b * 16 + kc) * 32 + v0], a0);
  atomicAdd(&ws[O_LC + (size_t)(b * 16 + kc) * 32 + v1], a1);
}

// ---------------- kernel 5: lamp GEMM v4 ----------------
// v2 shape (4 waves, 128 rows x 128 cols, grid (288,2)) + async global_load_lds
// B staging double-buffered + A register-gather 2 steps ahead; ONE barrier/step.
__global__ __launch_bounds__(256, 2) void k_lamp(float* __restrict__ ws,
                                                 float* __restrict__ out) {
  __shared__ __align__(16) char smem[33792];
  bf16x8* Bs16 = (bf16x8*)smem;            // 2 bufs x 512 units x 16B = 16384 B
  u32* Sw = (u32*)(smem + 16384);          // 2 bufs x 400 words = 3200 B
  float* Cs = (float*)smem;                // epilogue [64][132]

  const int t = threadIdx.x;
  const int bx = blockIdx.x;
  const int ni = bx / 6;
  const int sset = bx - ni * 6;
  const int s0 = (sset < 3) ? sset * 16 : (sset - 3) * 16 + 1;
  const int chalf = blockIdx.y;
  const int colbase = chalf * 128;
  const int w = t >> 6, lane = t & 63;
  const int wrow = w >> 1, wcol = w & 1;
  const int lr = lane & 15, quad = lane >> 4;

  const __bf16* vp = (const __bf16*)(ws + O_VP);
  const unsigned short* rp = (const unsigned short*)(ws + O_RT);

  // A staging map: 384 b32 units over 256 threads (t<128 take a second unit)
  const int kcA0 = t / 24, wpA0 = t - kcA0 * 24;
  const int ia1 = t + 256;
  const int kcA1 = ia1 / 24, wpA1 = ia1 - kcA1 * 24;
  const bool hasA1 = (t < 128);

  // B gll map: lane of wave w loads units u0 = w*64+lane, u1 = 256+w*64+lane
  const int u0 = w * 64 + lane, u1 = 256 + w * 64 + lane;
  const int cB0 = u0 >> 2, pB0 = ((u0 & 3) - ((u0 >> 3) & 3)) & 3;
  const int cB1 = u1 >> 2, pB1 = ((u1 & 3) - ((u1 >> 3) & 3)) & 3;
  const __bf16* gB0 = vp + (size_t)(colbase + cB0) * 3072 + pB0 * 8;
  const __bf16* gB1 = vp + (size_t)(colbase + cB1) * 3072 + pB1 * 8;
  char* ldsB0 = smem + w * 1024;           // + buf*8192 ; wave-uniform base
  char* ldsB1 = smem + 4096 + w * 1024;

  auto gatherA = [&](int ksn, u32& a0_, u32& a1_) {
    const int mi = ksn >> 1, mj0 = (ksn & 1) << 5;
    const int P0 = 96 * (mi - ni + 47) + mj0 - s0 + 33;
    long b0 = (long)kcA0 * 9216 + P0 + 2 * wpA0;
    if (P0 & 1) a0_ = (u32)rp[b0] | ((u32)rp[b0 + 1] << 16);
    else        a0_ = *(const u32*)(rp + b0);
    if (hasA1) {
      long b1 = (long)kcA1 * 9216 + P0 + 2 * wpA1;
      if (P0 & 1) a1_ = (u32)rp[b1] | ((u32)rp[b1 + 1] << 16);
      else        a1_ = *(const u32*)(rp + b1);
    }
  };

  f32x4 acc[4][4];
  {
    f32x4 zz = {0.f, 0.f, 0.f, 0.f};
#pragma unroll
    for (int i = 0; i < 4; ++i)
#pragma unroll
      for (int j = 0; j < 4; ++j) acc[i][j] = zz;
  }

  u32 a0 = 0, a1 = 0;
  // prologue: stage step 0, prefetch A(1)
  {
    u32 p0, p1 = 0;
    gatherA(0, p0, p1);
    Sw[kcA0 * 25 + wpA0] = p0;
    if (hasA1) Sw[kcA1 * 25 + wpA1] = p1;
    gll16(gB0, ldsB0);
    gll16(gB1, ldsB1);
    gatherA(1, a0, a1);
  }
  __syncthreads();

  for (int ks = 0; ks < NK; ++ks) {
    const int cur = ks & 1, nxt = cur ^ 1;
    if (ks + 1 < NK) {
      const int k0n = (ks + 1) * 32;
      gll16(gB0 + k0n, ldsB0 + nxt * 8192);
      gll16(gB1 + k0n, ldsB1 + nxt * 8192);
      Sw[nxt * 400 + kcA0 * 25 + wpA0] = a0;
      if (hasA1) Sw[nxt * 400 + kcA1 * 25 + wpA1] = a1;
    }
    if (ks + 2 < NK) gatherA(ks + 2, a0, a1);

    bf16x8 af[4], bfr[4];
#pragma unroll
    for (int rt = 0; rt < 4; ++rt) {
      int nl = wrow * 4 + rt;
      int wb = cur * 400 + lr * 25 + (7 - nl) + quad * 4;
      u32x4 dd = { Sw[wb], Sw[wb + 1], Sw[wb + 2], Sw[wb + 3] };
      af[rt] = __builtin_bit_cast(bf16x8, dd);
    }
#pragma unroll
    for (int ct = 0; ct < 4; ++ct) {
      int col = wcol * 64 + ct * 16 + lr;
      bfr[ct] = Bs16[cur * 512 + col * 4 + ((quad + (col >> 1)) & 3)];
    }
#pragma unroll
    for (int rt = 0; rt < 4; ++rt)
#pragma unroll
      for (int ct = 0; ct < 4; ++ct)
        acc[rt][ct] = __builtin_amdgcn_mfma_f32_16x16x32_bf16(af[rt], bfr[ct], acc[rt][ct], 0, 0, 0);
    __syncthreads();
  }

  // epilogue: Y = sum_kc Qp * (lamp + lamc*dinv)
  const float* lamcp = ws + O_LC;
  const float* Qp = ws + O_QP;
  __bf16* CRb = (__bf16*)(ws + O_CR);
  const int s = t >> 5, vv = t & 31;

  for (int h = 0; h < 2; ++h) {
    __syncthreads();
    if (wrow == h) {
#pragma unroll
      for (int rt = 0; rt < 4; ++rt) {
#pragma unroll
        for (int ct = 0; ct < 4; ++ct) {
          int col = wcol * 64 + ct * 16 + lr;
          int bb = chalf * 4 + (col >> 5);
          int vl = col & 31;
#pragma unroll
          for (int reg = 0; reg < 4; ++reg) {
            int row = rt * 16 + quad * 4 + reg;
            int kc = row & 15;
            float dinv = ws[O_ST + 192 + bb * 16 + kc];
            Cs[row * 132 + col] = acc[rt][ct][reg] + lamcp[(bb * 16 + kc) * 32 + vl] * dinv;
          }
        }
      }
    }
    __syncthreads();
#pragma unroll
    for (int i = 0; i < 16; ++i) {
      int combo = s * 16 + i;
      int hp = combo & 7, bl = (combo >> 3) & 3, nr = combo >> 5;
      int n = ni * 48 + s0 + 2 * (h * 4 + nr);
      int bb = chalf * 4 + bl;
      const float* qrow = Qp + ((size_t)(n * 8 + bb) * 8 + hp) * 16;
      const float* crow = Cs + (nr * 16) * 132 + bl * 32 + vv;
      float y = 0.f;
#pragma unroll
      for (int kc = 0; kc < 16; ++kc) y += qrow[kc] * crow[kc * 132];
      size_t idx = (size_t)(bb * NNPOS + n) * 128 + (hp & 3) * 32 + vv;
      if (hp < 4) out[idx] = y;
      else        CRb[idx] = (__bf16)y;
    }
  }
}

// ---------------- kernel: motion via MFMA ----------------
__global__ __launch_bounds__(256) void k_motion(const float* __restrict__ cor,
                                                float* __restrict__ ws,
                                                float* __restrict__ out) {
  const int t = threadIdx.x;
  const int wave = t >> 6, lane = t & 63;
  const int lr = lane & 15, quad = lane >> 4;
  const int r0 = blockIdx.x * 64 + wave * 16;
  const __bf16* crb = (const __bf16*)(ws + O_CR);
  const __bf16* wfb = (const __bf16*)(ws + O_WFB);

  f32x4 acc[8];
#pragma unroll
  for (int i = 0; i < 8; ++i) acc[i] = (f32x4){0.f, 0.f, 0.f, 0.f};

#pragma unroll
  for (int ks = 0; ks < 4; ++ks) {
    bf16x8 af = *(const bf16x8*)(crb + (size_t)(r0 + lr) * 128 + ks * 32 + quad * 8);
#pragma unroll
    for (int ct = 0; ct < 8; ++ct) {
      bf16x8 bfrag = *(const bf16x8*)(wfb + (ct * 16 + lr) * 128 + ks * 32 + quad * 8);
      acc[ct] = __builtin_amdgcn_mfma_f32_16x16x32_bf16(af, bfrag, acc[ct], 0, 0, 0);
    }
  }

#pragma unroll
  for (int reg = 0; reg < 4; ++reg) {
    int row = r0 + quad * 4 + reg;
    float c0 = cor[row * 2], c1 = cor[row * 2 + 1];
#pragma unroll
    for (int ct = 0; ct < 8; ++ct) {
      int o2 = ct * 16 + lr;
      float y = acc[ct][reg] + ws[O_B2 + o2] - c0 * ws[O_WG + o2 * 2] - c1 * ws[O_WG + o2 * 2 + 1];
      out[2359296ul + (size_t)row * 128 + o2] = y;
    }
  }
}

// ---------------- launcher ----------------
extern "C" void kernel_launch(void* const* d_in, const int* in_sizes, int n_in,
                              void* d_out, int out_size, void* d_ws, size_t ws_size,
                              hipStream_t stream) {
  const float* x   = (const float*)d_in[0];
  const float* cor = (const float*)d_in[1];
  const float* Wq  = (const float*)d_in[2];
  const float* Wk  = (const float*)d_in[3];
  const float* Wv  = (const float*)d_in[4];
  const float* Wce = (const float*)d_in[5];
  const float* bce = (const float*)d_in[6];
  const float* Wcc = (const float*)d_in[7];
  const float* Wmp = (const float*)d_in[8];
  const float* bmp = (const float*)d_in[9];
  const float* gq  = (const float*)d_in[10];
  const float* bq  = (const float*)d_in[11];
  const float* gv  = (const float*)d_in[12];
  const float* bv  = (const float*)d_in[13];
  const float* rel = (const float*)d_in[14];
  float* out = (float*)d_out;
  float* ws  = (float*)d_ws;

  k_fold  <<<64, 256, 0, stream>>>(Wcc, Wce, Wmp, bmp, bce, Wq, Wk, Wv, ws);
  k_qkv   <<<288, 256, 0, stream>>>(x, ws);
  k_rt    <<<565, 256, 0, stream>>>(rel, ws);
  k_zero  <<<96, 256, 0, stream>>>(ws);
  k_stats1<<<160, 256, 0, stream>>>(ws);
  k_stats2<<<1, 256, 0, stream>>>(gq, bq, gv, bv, ws);
  k_vp    <<<384, 256, 0, stream>>>(ws);
  k_lamc  <<<288, 256, 0, stream>>>(ws);
  k_prep  <<<2304, 256, 0, stream>>>(cor, Wce, bce, ws);
  k_lamp  <<<dim3(288, 2), 256, 0, stream>>>(ws, out);
  k_motion<<<288, 256, 0, stream>>>(cor, ws, out);
}

// Round 7
// 252.787 us; speedup vs baseline: 1.1810x; 1.0601x over previous
//
#include <hip/hip_runtime.h>
#include <math.h>
#include <stdint.h>

// ---------------- constants ----------------
#define NNPOS 2304            // 48*48
#define ROWS  18432           // 8 * 2304
#define NK    96              // K-steps total: 48 mi-blocks x 2 halves of padded-64

// workspace layout (float offsets)
#define O_Q   0ul             // q_raw [row][64]
#define O_K   1179648ul       // k_raw [row][16]
#define O_V   1474560ul       // v_raw [row][32]
#define O_ST  2064384ul       // scale_q[64] bias_q[64] scale_v[32] bias_v[32] denomInv[128]
#define O_VP  2064704ul       // Vp_g bf16 [256][3072] padded
#define O_QP  2457920ul       // Qp fp32 [n][b][8][16]
#define O_LC  4817216ul       // lamc raw sums [b][16][32]
#define O_RT  6000960ul       // R_T bf16 [16][9216]
#define O_WG  6148416ul       // Wg fp32 [o2][2] = Wmp@Wce
#define O_B2  6148672ul       // b2 fp32 [o2] = bmp - Wmp@bce
#define O_WB  6148800ul       // Wb bf16 [112][128]
#define O_PT  6155968ul       // part_q [64][128]
#define O_PV  6164160ul       // part_v [32][64]
#define O_PE  6166208ul       // part_e [8][8][16]
#define O_WFB 6167232ul       // Wf bf16 [128 o2][128 c]
#define O_CRF 6175424ul       // cor_reverse_ fp32 [row][128] (atomic accum)

typedef __bf16 bf16x8 __attribute__((ext_vector_type(8)));
typedef float  f32x4  __attribute__((ext_vector_type(4)));
typedef unsigned int u32;
typedef u32 u32x4 __attribute__((ext_vector_type(4)));

// ---------------- kernel: fold motion weights + convert qkv weights to bf16 ----------------
__global__ void k_fold(const float* __restrict__ Wcc, const float* __restrict__ Wce,
                       const float* __restrict__ Wmp, const float* __restrict__ bmp,
                       const float* __restrict__ bce, const float* __restrict__ Wq,
                       const float* __restrict__ Wk, const float* __restrict__ Wv,
                       float* __restrict__ ws) {
  const int t = threadIdx.x;
  const int g = blockIdx.x * 256 + t;
  const int o2 = g >> 7, c = g & 127;
  float acc = 0.f;
#pragma unroll 8
  for (int o = 0; o < 64; ++o) acc += Wmp[o2 * 64 + o] * Wcc[o * 128 + c];
  ((__bf16*)(ws + O_WFB))[o2 * 128 + c] = (__bf16)acc;
  if (blockIdx.x == 0 && t < 128) {
    float a0 = 0.f, a1 = 0.f, ab = 0.f;
#pragma unroll 8
    for (int o = 0; o < 64; ++o) {
      float w = Wmp[t * 64 + o];
      a0 += w * Wce[o * 2]; a1 += w * Wce[o * 2 + 1]; ab += w * bce[o];
    }
    ws[O_WG + t * 2] = a0; ws[O_WG + t * 2 + 1] = a1; ws[O_B2 + t] = bmp[t] - ab;
  }
  __bf16* wbp = (__bf16*)(ws + O_WB);
  if (g < 14336) {
    float w;
    if (g < 8192) w = Wq[g];
    else if (g < 10240) w = Wk[g - 8192];
    else w = Wv[g - 10240];
    wbp[g] = (__bf16)w;
  }
}

// ---------------- kernel 1: q,k,v via MFMA ----------------
__global__ __launch_bounds__(256) void k_qkv(const float* __restrict__ x,
                                             float* __restrict__ ws) {
  const int t = threadIdx.x;
  const int wave = t >> 6, lane = t & 63;
  const int lr = lane & 15, quad = lane >> 4;
  const int r0 = blockIdx.x * 64 + wave * 16;
  const int b = r0 / NNPOS;
  const int n0 = r0 - b * NNPOS;
  const size_t outbase = (size_t)(((b + 4) & 7)) * NNPOS + n0;

  const __bf16* wb = (const __bf16*)(ws + O_WB);
  const float* xrow = x + (size_t)(r0 + lr) * 128;

  f32x4 acc[7];
#pragma unroll
  for (int i = 0; i < 7; ++i) acc[i] = (f32x4){0.f, 0.f, 0.f, 0.f};

#pragma unroll
  for (int ks = 0; ks < 4; ++ks) {
    const float* ap = xrow + ks * 32 + quad * 8;
    float4 a0 = *(const float4*)(ap);
    float4 a1 = *(const float4*)(ap + 4);
    bf16x8 af;
    af[0] = (__bf16)a0.x; af[1] = (__bf16)a0.y; af[2] = (__bf16)a0.z; af[3] = (__bf16)a0.w;
    af[4] = (__bf16)a1.x; af[5] = (__bf16)a1.y; af[6] = (__bf16)a1.z; af[7] = (__bf16)a1.w;
#pragma unroll
    for (int ct = 0; ct < 7; ++ct) {
      bf16x8 bfrag = *(const bf16x8*)(wb + (ct * 16 + lr) * 128 + ks * 32 + quad * 8);
      acc[ct] = __builtin_amdgcn_mfma_f32_16x16x32_bf16(af, bfrag, acc[ct], 0, 0, 0);
    }
  }

#pragma unroll
  for (int ct = 0; ct < 7; ++ct) {
#pragma unroll
    for (int reg = 0; reg < 4; ++reg) {
      int m = quad * 4 + reg;
      int oc = ct * 16 + lr;
      float vvv = acc[ct][reg];
      if (ct < 4)      ws[O_Q + (size_t)(r0 + m) * 64 + oc] = vvv;
      else if (ct < 5) ws[O_K + (outbase + m) * 16 + (oc - 64)] = vvv;
      else             ws[O_V + (outbase + m) * 32 + (oc - 80)] = vvv;
    }
  }
}

// ---------------- kernel: transpose rel_pos_emb -> R_T bf16 [16][96*96] ----------------
__global__ void k_rt(const float* __restrict__ rel, float* __restrict__ ws) {
  __bf16* rt = (__bf16*)(ws + O_RT);
  int i = blockIdx.x * 256 + threadIdx.x;
  if (i < 144400) {
    int kc = i & 15, rr = i >> 4;
    int ri = rr / 95, rj = rr - ri * 95;
    rt[(size_t)kc * 9216 + ri * 96 + rj] = (__bf16)rel[i];
  }
}

// ---------------- kernel: zero Vp pad + lamc accumulator ----------------
__global__ void k_zero(float* __restrict__ ws) {
  __bf16* vp = (__bf16*)(ws + O_VP);
  int i = blockIdx.x * 256 + threadIdx.x;   // < 24576
  if (i < 4096) ws[O_LC + i] = 0.f;
  int bv = i / 96, rem = i - bv * 96;
  int mi = rem >> 1, h8 = rem & 1;
  uint4 z; z.x = 0; z.y = 0; z.z = 0; z.w = 0;
  *(uint4*)(vp + (size_t)bv * 3072 + mi * 64 + 48 + h8 * 8) = z;
}

// ---------------- kernel: zero atomic-accumulated outputs (app part of out, CRF) ----------------
__global__ void k_zout(float* __restrict__ out, float* __restrict__ ws) {
  size_t i = (size_t)blockIdx.x * 256 + threadIdx.x;   // 589824 float4 units
  f32x4 z = {0.f, 0.f, 0.f, 0.f};
  ((f32x4*)out)[i] = z;
  ((f32x4*)(ws + O_CRF))[i] = z;
}

// ---------------- kernel 2a: stats partials (coalesced) ----------------
__global__ void k_stats1(float* __restrict__ ws) {
  const int t = threadIdx.x, blk = blockIdx.x;
  __shared__ float sh[512];
  if (blk < 64) {
    const int ch = t & 63, rsub = t >> 6;
    const float* src = ws + O_Q;
    const int r0 = blk * 288;
    float s = 0.f, s2 = 0.f;
#pragma unroll 4
    for (int i = 0; i < 72; ++i) {
      float v = src[(size_t)(r0 + rsub + i * 4) * 64 + ch];
      s += v; s2 += v * v;
    }
    sh[t] = s; sh[256 + t] = s2;
    __syncthreads();
    if (t < 64) {
      float S = sh[t] + sh[t + 64] + sh[t + 128] + sh[t + 192];
      float S2 = sh[256 + t] + sh[256 + t + 64] + sh[256 + t + 128] + sh[256 + t + 192];
      ws[O_PT + blk * 128 + t * 2] = S; ws[O_PT + blk * 128 + t * 2 + 1] = S2;
    }
  } else if (blk < 96) {
    const int j = blk - 64;
    const int ch = t & 31, rsub = t >> 5;
    const float* src = ws + O_V;
    const int r0 = j * 576;
    float s = 0.f, s2 = 0.f;
#pragma unroll 4
    for (int i = 0; i < 72; ++i) {
      float v = src[(size_t)(r0 + rsub + i * 8) * 32 + ch];
      s += v; s2 += v * v;
    }
    sh[t] = s; sh[256 + t] = s2;
    __syncthreads();
    if (t < 32) {
      float S = 0.f, S2 = 0.f;
#pragma unroll
      for (int k = 0; k < 8; ++k) { S += sh[t + k * 32]; S2 += sh[256 + t + k * 32]; }
      ws[O_PV + j * 64 + t * 2] = S; ws[O_PV + j * 64 + t * 2 + 1] = S2;
    }
  } else {
    const int idx = blk - 96;
    const int b = idx >> 3, sl = idx & 7;
    const int kc = t & 15, rsub = t >> 4;
    const int r0 = b * 2304 + sl * 288;
    float s = 0.f;
#pragma unroll 2
    for (int i = 0; i < 18; ++i)
      s += __expf(ws[O_K + (size_t)(r0 + rsub + i * 16) * 16 + kc]);
    sh[t] = s;
    __syncthreads();
    if (t < 16) {
      float S = 0.f;
#pragma unroll
      for (int k = 0; k < 16; ++k) S += sh[t + k * 16];
      ws[O_PE + b * 128 + sl * 16 + t] = S;
    }
  }
}

// ---------------- kernel 2b: finalize stats ----------------
__global__ void k_stats2(const float* __restrict__ gq, const float* __restrict__ bq,
                         const float* __restrict__ gv, const float* __restrict__ bv,
                         float* __restrict__ ws) {
  const int t = threadIdx.x;
  if (t < 64) {
    float S = 0.f, S2 = 0.f;
    for (int i = 0; i < 64; ++i) { S += ws[O_PT + i * 128 + t * 2]; S2 += ws[O_PT + i * 128 + t * 2 + 1]; }
    float mu = S / 18432.f, var = S2 / 18432.f - mu * mu;
    float sc = gq[t] * rsqrtf(var + 1e-5f);
    ws[O_ST + t] = sc; ws[O_ST + 64 + t] = bq[t] - mu * sc;
  } else if (t < 96) {
    int ch = t - 64;
    float S = 0.f, S2 = 0.f;
    for (int i = 0; i < 32; ++i) { S += ws[O_PV + i * 64 + ch * 2]; S2 += ws[O_PV + i * 64 + ch * 2 + 1]; }
    float mu = S / 18432.f, var = S2 / 18432.f - mu * mu;
    float sc = gv[ch] * rsqrtf(var + 1e-5f);
    ws[O_ST + 128 + ch] = sc; ws[O_ST + 160 + ch] = bv[ch] - mu * sc;
  } else if (t < 224) {
    int idx = t - 96; int b = idx >> 4, kc = idx & 15;
    float S = 0.f;
#pragma unroll
    for (int sl = 0; sl < 8; ++sl) S += ws[O_PE + b * 128 + sl * 16 + kc];
    ws[O_ST + 192 + idx] = 1.f / S;
  }
}

// ---------------- kernel: build Vp_g via LDS transpose ----------------
__global__ void k_vp(float* __restrict__ ws) {
  const int b = blockIdx.x / 48, mi = blockIdx.x - b * 48;
  const int t = threadIdx.x;
  __shared__ float Vn[48 * 33];
  const float* st = ws + O_ST;
  const int r0 = b * 2304 + mi * 48;
#pragma unroll
  for (int i = t; i < 1536; i += 256) {
    int r = i >> 5, j = i & 31;
    Vn[r * 33 + j] = ws[O_V + (size_t)(r0 + r) * 32 + j] * st[128 + j] + st[160 + j];
  }
  __syncthreads();
  __bf16* vp = (__bf16*)(ws + O_VP);
  const int j = t >> 3, seg = t & 7;
  unsigned short u[6];
#pragma unroll
  for (int q = 0; q < 6; ++q)
    u[q] = __builtin_bit_cast(unsigned short, (__bf16)Vn[(seg * 6 + q) * 33 + j]);
  u32 w0 = (u32)u[0] | ((u32)u[1] << 16);
  u32 w1 = (u32)u[2] | ((u32)u[3] << 16);
  u32 w2 = (u32)u[4] | ((u32)u[5] << 16);
  u32* dst = (u32*)(vp + (size_t)(b * 32 + j) * 3072 + mi * 64 + seg * 6);
  dst[0] = w0; dst[1] = w1; dst[2] = w2;
}

// ---------------- kernel 3: Qp (Q' + cor_embed 8 virtual heads) ----------------
__global__ void k_prep(const float* __restrict__ cor, const float* __restrict__ Wce,
                       const float* __restrict__ bce, float* __restrict__ ws) {
  const int t = threadIdx.x;
  const int rl = t >> 5, j = t & 31;
  const int rid = blockIdx.x * 8 + rl;
  const int b = rid / NNPOS, n = rid - b * NNPOS;
  const float* st = ws + O_ST;
  float c0 = cor[rid * 2], c1 = cor[rid * 2 + 1];
#pragma unroll
  for (int ch = j; ch < 64; ch += 32) {
    float qn = ws[O_Q + (size_t)rid * 64 + ch] * st[ch] + st[64 + ch];
    ws[O_QP + (size_t)(n * 8 + b) * 128 + ch] = qn;
    float ce = c0 * Wce[ch * 2] + c1 * Wce[ch * 2 + 1] + bce[ch];
    ws[O_QP + (size_t)(n * 8 + b) * 128 + 64 + ch] = ce;
  }
}

// ---------------- kernel 4: lamc raw sums (288 blocks, LDS-staged, atomic) ----------------
__global__ void k_lamc(float* __restrict__ ws) {
  const int b = blockIdx.x / 36, sl = blockIdx.x - b * 36;
  const int t = threadIdx.x;
  __shared__ float eK[16][16];
  __shared__ float Vn[16][33];
  const float* st = ws + O_ST;
  const int kc = t & 15, vp_ = t >> 4;
  const int v0 = vp_ * 2, v1 = v0 + 1;
  float a0 = 0.f, a1 = 0.f;
  const int m0 = b * 2304 + sl * 64;
  const int jj = t & 31, rw = t >> 5;
  const float scj = st[128 + jj], bij = st[160 + jj];
  for (int ch = 0; ch < 4; ++ch) {
    const int mbase = m0 + ch * 16;
    eK[t >> 4][t & 15] = __expf(ws[O_K + (size_t)(mbase + (t >> 4)) * 16 + (t & 15)]);
    Vn[rw][jj]     = ws[O_V + (size_t)(mbase + rw) * 32 + jj] * scj + bij;
    Vn[rw + 8][jj] = ws[O_V + (size_t)(mbase + rw + 8) * 32 + jj] * scj + bij;
    __syncthreads();
#pragma unroll
    for (int m = 0; m < 16; ++m) {
      float e = eK[m][kc];
      a0 += e * Vn[m][v0];
      a1 += e * Vn[m][v1];
    }
    __syncthreads();
  }
  atomicAdd(&ws[O_LC + (size_t)(b * 16 + kc) * 32 + v0], a0);
  atomicAdd(&ws[O_LC + (size_t)(b * 16 + kc) * 32 + v1], a1);
}

// ---------------- kernel 5: lamp GEMM v5 = proven v2 body + K-split over blockIdx.z ----------------
// grid (288, 2, 2): n-group x col-half x K-half. Each block: 128x128 over 48 K-steps.
// Epilogue applies Q' to the partial sum and atomicAdds into out / CRF (fp32).
__global__ __launch_bounds__(256, 2) void k_lamp(float* __restrict__ ws,
                                                 float* __restrict__ out) {
  __shared__ __align__(16) char smem[33792];
  bf16x8* Bs16 = (bf16x8*)smem;                  // 512 x 16B units (8 KB)
  u32* Sw = (u32*)(smem + 8192);                 // S[16][50] bf16 = 400 words
  float* Cs = (float*)smem;                      // epilogue [64][132]

  const int t = threadIdx.x;
  const int bx = blockIdx.x;
  const int ni = bx / 6;
  const int sset = bx - ni * 6;
  const int s0 = (sset < 3) ? sset * 16 : (sset - 3) * 16 + 1;
  const int chalf = blockIdx.y;
  const int khalf = blockIdx.z;
  const int ks0 = khalf * 48, ksE = ks0 + 48;
  const int colbase = chalf * 128;
  const int wave = t >> 6, lane = t & 63;
  const int wrow = wave >> 1, wcol = wave & 1;
  const int lr = lane & 15, quad = lane >> 4;

  const __bf16* vp = (const __bf16*)(ws + O_VP);
  const unsigned short* rp = (const unsigned short*)(ws + O_RT);

  const int ia0 = t;
  const int kcA0 = ia0 / 24, wpA0 = ia0 - kcA0 * 24;
  const int ia1 = t + 256;
  const int kcA1 = ia1 / 24, wpA1 = ia1 - kcA1 * 24;
  const bool hasA1 = (ia1 < 384);

  const int colB0 = t >> 2, pB0 = ((t & 3) - ((t >> 3) & 3)) & 3;
  const int ub1 = t + 256;
  const int colB1 = ub1 >> 2, pB1 = ((ub1 & 3) - ((ub1 >> 3) & 3)) & 3;
  const __bf16* gB0 = vp + (size_t)(colbase + colB0) * 3072 + pB0 * 8;
  const __bf16* gB1 = vp + (size_t)(colbase + colB1) * 3072 + pB1 * 8;

  f32x4 acc[4][4];
  {
    f32x4 zz = {0.f, 0.f, 0.f, 0.f};
#pragma unroll
    for (int i = 0; i < 4; ++i)
#pragma unroll
      for (int j = 0; j < 4; ++j) acc[i][j] = zz;
  }

  u32 sa0 = 0, sa1 = 0;
  bf16x8 vb0, vb1;

  auto loadStep = [&](int ksn) {
    const int mi = ksn >> 1, mj0 = (ksn & 1) << 5;
    const int P0 = 96 * (mi - ni + 47) + mj0 - s0 + 33;
    const int k0 = ksn * 32;
    long b0 = (long)kcA0 * 9216 + P0 + 2 * wpA0;
    if (P0 & 1) sa0 = (u32)rp[b0] | ((u32)rp[b0 + 1] << 16);
    else        sa0 = *(const u32*)(rp + b0);
    if (hasA1) {
      long b1 = (long)kcA1 * 9216 + P0 + 2 * wpA1;
      if (P0 & 1) sa1 = (u32)rp[b1] | ((u32)rp[b1 + 1] << 16);
      else        sa1 = *(const u32*)(rp + b1);
    }
    vb0 = *(const bf16x8*)(gB0 + k0);
    vb1 = *(const bf16x8*)(gB1 + k0);
  };

  loadStep(ks0);

  for (int ks = ks0; ks < ksE; ++ks) {
    __syncthreads();
    Sw[kcA0 * 25 + wpA0] = sa0;
    if (hasA1) Sw[kcA1 * 25 + wpA1] = sa1;
    Bs16[t] = vb0;
    Bs16[t + 256] = vb1;
    __syncthreads();

    if (ks + 1 < ksE) loadStep(ks + 1);

    bf16x8 af[4], bfr[4];
#pragma unroll
    for (int rt = 0; rt < 4; ++rt) {
      int nl = wrow * 4 + rt;
      int wb = lr * 25 + (7 - nl) + quad * 4;
      u32x4 dd = { Sw[wb], Sw[wb + 1], Sw[wb + 2], Sw[wb + 3] };
      af[rt] = __builtin_bit_cast(bf16x8, dd);
    }
#pragma unroll
    for (int ct = 0; ct < 4; ++ct) {
      int col = wcol * 64 + ct * 16 + lr;
      int u = col * 4 + ((quad + (col >> 1)) & 3);
      bfr[ct] = Bs16[u];
    }
#pragma unroll
    for (int rt = 0; rt < 4; ++rt)
#pragma unroll
      for (int ct = 0; ct < 4; ++ct)
        acc[rt][ct] = __builtin_amdgcn_mfma_f32_16x16x32_bf16(af[rt], bfr[ct], acc[rt][ct], 0, 0, 0);
  }

  // epilogue: y_partial = sum_kc Qp * (lamp_half + [khalf==0] lamc*dinv); atomicAdd out/CRF
  const float* lamcp = ws + O_LC;
  const float* Qp = ws + O_QP;
  float* crf = ws + O_CRF;
  const int s = t >> 5, vv = t & 31;

  for (int h = 0; h < 2; ++h) {
    __syncthreads();
    if (wrow == h) {
#pragma unroll
      for (int rt = 0; rt < 4; ++rt) {
#pragma unroll
        for (int ct = 0; ct < 4; ++ct) {
          int col = wcol * 64 + ct * 16 + lr;
          int bb = chalf * 4 + (col >> 5);
          int vl = col & 31;
#pragma unroll
          for (int reg = 0; reg < 4; ++reg) {
            int row = rt * 16 + quad * 4 + reg;
            int kc = row & 15;
            float add = 0.f;
            if (khalf == 0) {
              float dinv = ws[O_ST + 192 + bb * 16 + kc];
              add = lamcp[(bb * 16 + kc) * 32 + vl] * dinv;
            }
            Cs[row * 132 + col] = acc[rt][ct][reg] + add;
          }
        }
      }
    }
    __syncthreads();
#pragma unroll
    for (int i = 0; i < 16; ++i) {
      int combo = s * 16 + i;
      int hp = combo & 7, bl = (combo >> 3) & 3, nr = combo >> 5;
      int n = ni * 48 + s0 + 2 * (h * 4 + nr);
      int bb = chalf * 4 + bl;
      const float* qrow = Qp + ((size_t)(n * 8 + bb) * 8 + hp) * 16;
      const float* crow = Cs + (nr * 16) * 132 + bl * 32 + vv;
      float y = 0.f;
#pragma unroll
      for (int kc = 0; kc < 16; ++kc) y += qrow[kc] * crow[kc * 132];
      size_t idx = (size_t)(bb * NNPOS + n) * 128 + (hp & 3) * 32 + vv;
      if (hp < 4) atomicAdd(&out[idx], y);
      else        atomicAdd(&crf[idx], y);
    }
  }
}

// ---------------- kernel: motion via MFMA (CRF fp32 -> bf16 frags) ----------------
__global__ __launch_bounds__(256) void k_motion(const float* __restrict__ cor,
                                                float* __restrict__ ws,
                                                float* __restrict__ out) {
  const int t = threadIdx.x;
  const int wave = t >> 6, lane = t & 63;
  const int lr = lane & 15, quad = lane >> 4;
  const int r0 = blockIdx.x * 64 + wave * 16;
  const float* crf = ws + O_CRF;
  const __bf16* wfb = (const __bf16*)(ws + O_WFB);

  f32x4 acc[8];
#pragma unroll
  for (int i = 0; i < 8; ++i) acc[i] = (f32x4){0.f, 0.f, 0.f, 0.f};

#pragma unroll
  for (int ks = 0; ks < 4; ++ks) {
    const float* ap = crf + (size_t)(r0 + lr) * 128 + ks * 32 + quad * 8;
    float4 a0 = *(const float4*)(ap);
    float4 a1 = *(const float4*)(ap + 4);
    bf16x8 af;
    af[0] = (__bf16)a0.x; af[1] = (__bf16)a0.y; af[2] = (__bf16)a0.z; af[3] = (__bf16)a0.w;
    af[4] = (__bf16)a1.x; af[5] = (__bf16)a1.y; af[6] = (__bf16)a1.z; af[7] = (__bf16)a1.w;
#pragma unroll
    for (int ct = 0; ct < 8; ++ct) {
      bf16x8 bfrag = *(const bf16x8*)(wfb + (ct * 16 + lr) * 128 + ks * 32 + quad * 8);
      acc[ct] = __builtin_amdgcn_mfma_f32_16x16x32_bf16(af, bfrag, acc[ct], 0, 0, 0);
    }
  }

#pragma unroll
  for (int reg = 0; reg < 4; ++reg) {
    int row = r0 + quad * 4 + reg;
    float c0 = cor[row * 2], c1 = cor[row * 2 + 1];
#pragma unroll
    for (int ct = 0; ct < 8; ++ct) {
      int o2 = ct * 16 + lr;
      float y = acc[ct][reg] + ws[O_B2 + o2] - c0 * ws[O_WG + o2 * 2] - c1 * ws[O_WG + o2 * 2 + 1];
      out[2359296ul + (size_t)row * 128 + o2] = y;
    }
  }
}

// ---------------- launcher ----------------
extern "C" void kernel_launch(void* const* d_in, const int* in_sizes, int n_in,
                              void* d_out, int out_size, void* d_ws, size_t ws_size,
                              hipStream_t stream) {
  const float* x   = (const float*)d_in[0];
  const float* cor = (const float*)d_in[1];
  const float* Wq  = (const float*)d_in[2];
  const float* Wk  = (const float*)d_in[3];
  const float* Wv  = (const float*)d_in[4];
  const float* Wce = (const float*)d_in[5];
  const float* bce = (const float*)d_in[6];
  const float* Wcc = (const float*)d_in[7];
  const float* Wmp = (const float*)d_in[8];
  const float* bmp = (const float*)d_in[9];
  const float* gq  = (const float*)d_in[10];
  const float* bq  = (const float*)d_in[11];
  const float* gv  = (const float*)d_in[12];
  const float* bv  = (const float*)d_in[13];
  const float* rel = (const float*)d_in[14];
  float* out = (float*)d_out;
  float* ws  = (float*)d_ws;

  k_fold  <<<64, 256, 0, stream>>>(Wcc, Wce, Wmp, bmp, bce, Wq, Wk, Wv, ws);
  k_qkv   <<<288, 256, 0, stream>>>(x, ws);
  k_rt    <<<565, 256, 0, stream>>>(rel, ws);
  k_zero  <<<96, 256, 0, stream>>>(ws);
  k_zout  <<<2304, 256, 0, stream>>>(out, ws);
  k_stats1<<<160, 256, 0, stream>>>(ws);
  k_stats2<<<1, 256, 0, stream>>>(gq, bq, gv, bv, ws);
  k_vp    <<<384, 256, 0, stream>>>(ws);
  k_lamc  <<<288, 256, 0, stream>>>(ws);
  k_prep  <<<2304, 256, 0, stream>>>(cor, Wce, bce, ws);
  k_lamp  <<<dim3(288, 2, 2), 256, 0, stream>>>(ws, out);
  k_motion<<<288, 256, 0, stream>>>(cor, ws, out);
}